// Round 2
// baseline (916.260 us; speedup 1.0000x reference)
//
#include <hip/hip_runtime.h>
#include <stdint.h>

typedef unsigned short u16;
typedef unsigned int u32;
typedef __attribute__((ext_vector_type(8))) short bf16x8;
typedef __attribute__((ext_vector_type(4))) float f32x4;

#define S_LEN 4032
#define S_PAD 4096
#define DIMC  1536
#define HD    128
#define FRAME 448

// ---- workspace layout (bytes) ----
static const size_t OFF_FLAG  = 0;
static const size_t OFF_CANON = 256;
static const size_t OFF_XB    = 524288;                    // 4096x1536 bf16
static const size_t OFF_WT    = OFF_XB  + 12582912;        // 4608x1536 bf16
static const size_t OFF_WOT   = OFF_WT  + 14155776;        // 1536x1536 bf16
static const size_t OFF_YQ    = OFF_WOT + 4718592;         // 4096x1536 bf16
static const size_t OFF_YK    = OFF_YQ  + 12582912;
static const size_t OFF_VT    = OFF_YK  + 12582912;        // 1536x4096 bf16 (V^T)
static const size_t OFF_QH    = OFF_VT  + 12582912;        // 12x4032x128 bf16
static const size_t OFF_KH    = OFF_QH  + 12386304;
static const size_t OFF_AT    = OFF_KH  + 12386304;        // 4096x1536 bf16
static const size_t WS_NEED   = OFF_AT  + 12582912;

#define C_BQ 0
#define C_BO 4608
#define C_GQ 6144
#define C_GK 7680
#define C_FR 9216
#define C_TOT 74752

__device__ __forceinline__ u16 f2bf(float f) {
  union { float f; u32 u; } v; v.f = f;
  u32 u = v.u;
  u32 r = (u + 0x7fffu + ((u >> 16) & 1u)) >> 16;
  return (u16)r;
}
__device__ __forceinline__ float bf2f(u16 h) {
  union { float f; u32 u; } v; v.u = ((u32)h) << 16;
  return v.f;
}

__device__ __forceinline__ void gld_lds16(const void* g, void* l) {
  __builtin_amdgcn_global_load_lds(
      (const __attribute__((address_space(1))) void*)(uintptr_t)g,
      (__attribute__((address_space(3))) void*)(u32)(uintptr_t)l,
      16, 0, 0);
}

__device__ __forceinline__ f32x4 mfma16(bf16x8 a, bf16x8 b, f32x4 c) {
  return __builtin_amdgcn_mfma_f32_16x16x32_bf16(a, b, c, 0, 0, 0);
}

// ---------------- dtype detection ----------------
__global__ void detect_dtype(const u16* __restrict__ x, int* __restrict__ flag) {
  __shared__ int cnt;
  if (threadIdx.x == 0) cnt = 0;
  __syncthreads();
  int e = (x[2 * threadIdx.x] >> 7) & 0xff;
  if (e > 150) atomicAdd(&cnt, 1);
  __syncthreads();
  if (threadIdx.x == 0) *flag = (cnt >= 8) ? 1 : 0;  // 1 = fp32 inputs, 0 = bf16
}

// ---------------- small tensors -> canonical fp32 ----------------
__global__ void prep_small(const void* bq, const void* bk, const void* bv, const void* bo,
                           const void* gq, const void* gk, const void* fr,
                           float* __restrict__ canon, const int* __restrict__ flagp) {
  int fl = *flagp;
  for (int i = blockIdx.x * 256 + threadIdx.x; i < C_TOT; i += gridDim.x * 256) {
    const void* src; int j;
    if      (i < 1536) { src = bq; j = i; }
    else if (i < 3072) { src = bk; j = i - 1536; }
    else if (i < 4608) { src = bv; j = i - 3072; }
    else if (i < 6144) { src = bo; j = i - 4608; }
    else if (i < 7680) { src = gq; j = i - 6144; }
    else if (i < 9216) { src = gk; j = i - 7680; }
    else               { src = fr; j = i - 9216; }
    canon[i] = fl ? ((const float*)src)[j] : bf2f(((const u16*)src)[j]);
  }
}

// ---------------- x -> bf16, pad rows to 4096 ----------------
__global__ void convert_x(const void* __restrict__ xin, u16* __restrict__ xb,
                          const int* __restrict__ flagp) {
  int fl = *flagp;
  int i = blockIdx.x * 256 + threadIdx.x;
  if (i >= (S_PAD * DIMC) / 8) return;
  size_t base = (size_t)i * 8;
  int row = (int)(base / DIMC);
  union { u16 h[8]; uint4 v; } u;
  if (row < S_LEN) {
    if (fl) {
      const float* xf = (const float*)xin + base;
      #pragma unroll
      for (int j = 0; j < 8; j++) u.h[j] = f2bf(xf[j]);
    } else {
      const u16* xh = (const u16*)xin + base;
      #pragma unroll
      for (int j = 0; j < 8; j++) u.h[j] = xh[j];
    }
  } else {
    #pragma unroll
    for (int j = 0; j < 8; j++) u.h[j] = 0;
  }
  ((uint4*)xb)[i] = u.v;
}

// ---------------- W (K x N) -> Wt (N x K) bf16 ----------------
__global__ void transpose_w(const void* Wq, const void* Wk, const void* Wv, const void* Wo,
                            u16* __restrict__ wqkvt, u16* __restrict__ wot,
                            const int* __restrict__ flagp) {
  int fl = *flagp;
  int z = blockIdx.z;
  const void* W = (z == 0) ? Wq : (z == 1) ? Wk : (z == 2) ? Wv : Wo;
  u16* dst = (z < 3) ? (wqkvt + (size_t)z * DIMC * DIMC) : wot;
  __shared__ float tile[32][33];
  int tx = threadIdx.x, ty = threadIdx.y;
  int c = blockIdx.x * 32 + tx;
  #pragma unroll
  for (int i = 0; i < 4; i++) {
    int r = blockIdx.y * 32 + ty + i * 8;
    float v = fl ? ((const float*)W)[(size_t)r * DIMC + c]
                 : bf2f(((const u16*)W)[(size_t)r * DIMC + c]);
    tile[ty + i * 8][tx] = v;
  }
  __syncthreads();
  int k = blockIdx.y * 32 + tx;
  #pragma unroll
  for (int i = 0; i < 4; i++) {
    int n = blockIdx.x * 32 + ty + i * 8;
    dst[(size_t)n * DIMC + k] = f2bf(tile[tx][ty + i * 8]);
  }
}

// ---------------- GEMM: C(MxN) = A(MxK) @ Bt(NxK)^T + bias ----------------
template <int MODE>
__launch_bounds__(256, 2)
__global__ void gemm_bt(const u16* __restrict__ A, const u16* __restrict__ Bt,
                        const float* __restrict__ canon,
                        u16* __restrict__ Yq, u16* __restrict__ Yk, u16* __restrict__ Vt,
                        void* __restrict__ Out, const int* __restrict__ flagp) {
  const int bm0 = blockIdx.y * 128, bn0 = blockIdx.x * 128;
  const int tid = threadIdx.x, wave = tid >> 6, lane = tid & 63;
  const int wm = wave >> 1, wn = wave & 1;
  const int l15 = lane & 15, l4 = lane >> 4;
  __shared__ u16 sA[128 * 64];
  __shared__ u16 sB[128 * 64];
  f32x4 acc[4][4];
  #pragma unroll
  for (int i = 0; i < 4; i++)
    #pragma unroll
    for (int j = 0; j < 4; j++) acc[i][j] = (f32x4){0.f, 0.f, 0.f, 0.f};

  const u16* Ab = A  + (size_t)(bm0 + (lane >> 3)) * DIMC + (lane & 7) * 8;
  const u16* Bb = Bt + (size_t)(bn0 + (lane >> 3)) * DIMC + (lane & 7) * 8;

  for (int kt = 0; kt < DIMC; kt += 64) {
    __syncthreads();
    #pragma unroll
    for (int c = 0; c < 4; c++) {
      int g = wave * 4 + c;
      gld_lds16(Ab + (size_t)g * 8 * DIMC + kt, (char*)sA + g * 1024);
      gld_lds16(Bb + (size_t)g * 8 * DIMC + kt, (char*)sB + g * 1024);
    }
    __syncthreads();
    #pragma unroll
    for (int ks = 0; ks < 2; ks++) {
      const int ko = ks * 32 + l4 * 8;
      bf16x8 av[4], bvv[4];
      #pragma unroll
      for (int mt = 0; mt < 4; mt++) av[mt]  = *(const bf16x8*)(sA + (wm * 64 + mt * 16 + l15) * 64 + ko);
      #pragma unroll
      for (int nt = 0; nt < 4; nt++) bvv[nt] = *(const bf16x8*)(sB + (wn * 64 + nt * 16 + l15) * 64 + ko);
      #pragma unroll
      for (int mt = 0; mt < 4; mt++)
        #pragma unroll
        for (int nt = 0; nt < 4; nt++)
          acc[mt][nt] = mfma16(av[mt], bvv[nt], acc[mt][nt]);
    }
  }

  const int gm0 = bm0 + wm * 64;
  const int gn0 = bn0 + wn * 64;
  if (MODE == 0) {
    #pragma unroll
    for (int nt = 0; nt < 4; nt++) {
      int gn = gn0 + nt * 16 + l15;
      float b = canon[C_BQ + gn];
      #pragma unroll
      for (int mt = 0; mt < 4; mt++) {
        int gm = gm0 + mt * 16 + l4 * 4;
        if (gn < 1536) {
          #pragma unroll
          for (int r = 0; r < 4; r++)
            Yq[(size_t)(gm + r) * DIMC + gn] = f2bf(acc[mt][nt][r] + b);
        } else if (gn < 3072) {
          int g2 = gn - 1536;
          #pragma unroll
          for (int r = 0; r < 4; r++)
            Yk[(size_t)(gm + r) * DIMC + g2] = f2bf(acc[mt][nt][r] + b);
        } else {
          int g2 = gn - 3072;
          u32 lo = (u32)f2bf(acc[mt][nt][0] + b) | ((u32)f2bf(acc[mt][nt][1] + b) << 16);
          u32 hi = (u32)f2bf(acc[mt][nt][2] + b) | ((u32)f2bf(acc[mt][nt][3] + b) << 16);
          uint2 pk; pk.x = lo; pk.y = hi;
          *(uint2*)(Vt + (size_t)g2 * S_PAD + gm) = pk;
        }
      }
    }
  } else {
    const int fl = *flagp;
    #pragma unroll
    for (int nt = 0; nt < 4; nt++) {
      int gn = gn0 + nt * 16 + l15;
      float b = canon[C_BO + gn];
      #pragma unroll
      for (int mt = 0; mt < 4; mt++) {
        int gm = gm0 + mt * 16 + l4 * 4;
        #pragma unroll
        for (int r = 0; r < 4; r++) {
          int gr = gm + r;
          if (gr < S_LEN) {
            float v = acc[mt][nt][r] + b;
            if (fl) ((float*)Out)[(size_t)gr * DIMC + gn] = v;
            else    ((u16*)Out)[(size_t)gr * DIMC + gn] = f2bf(v);
          }
        }
      }
    }
  }
}

// ---------------- fused RMSNorm + RoPE (q and k in one launch) ----------------
// blockIdx.y == 0: q path (scaled by 1/sqrt(HD)); 1: k path
__global__ void norm_rope(const u16* __restrict__ Yq, const u16* __restrict__ Yk,
                          const float* __restrict__ canon, u16* __restrict__ Qh,
                          u16* __restrict__ Kh) {
  const int s = blockIdx.x;
  const int isq = (blockIdx.y == 0);
  const u16* Y = isq ? Yq : Yk;
  const float* g = canon + (isq ? C_GQ : C_GK);
  u16* Oh = isq ? Qh : Kh;
  const float sc = isq ? 0.08838834764831845f : 1.0f;
  const int tid = threadIdx.x, wave = tid >> 6, lane = tid & 63;
  __shared__ float row[DIMC];
  __shared__ float cs[64], sn[64];
  __shared__ float red[4];
  float ss = 0.f;
  for (int i = tid; i < DIMC; i += 256) {
    float v = bf2f(Y[(size_t)s * DIMC + i]);
    row[i] = v; ss += v * v;
  }
  #pragma unroll
  for (int d = 32; d; d >>= 1) ss += __shfl_down(ss, d, 64);
  if (lane == 0) red[wave] = ss;
  if (tid < 64) {
    int f_ = s / FRAME, hh = (s % FRAME) / 28, ww = s % 28;
    const float* fr = canon + C_FR;
    float a;
    if (tid < 22)      a = fr[f_ * 64 + tid];
    else if (tid < 43) a = fr[hh * 64 + tid];
    else               a = fr[ww * 64 + tid];
    float si, co;
    __sincosf(a, &si, &co);
    cs[tid] = co; sn[tid] = si;
  }
  __syncthreads();
  float rms = rsqrtf((red[0] + red[1] + red[2] + red[3]) * (1.f / 1536.f) + 1e-6f) ;
  for (int p = tid; p < 768; p += 256) {
    int head = p >> 6, jj = p & 63;
    float xr = row[2 * p]     * rms * g[2 * p];
    float xi = row[2 * p + 1] * rms * g[2 * p + 1];
    float c = cs[jj], s_ = sn[jj];
    u32 pk = (u32)f2bf((xr * c - xi * s_) * sc) | ((u32)f2bf((xr * s_ + xi * c) * sc) << 16);
    *(u32*)(Oh + ((size_t)head * S_LEN + s) * HD + 2 * jj) = pk;
  }
}

// ---------------- flash attention v2: one wave per 16-row Q tile, no barriers ----------------
// Computes S^T = K.Q^T (keys as C rows), softmax over keys = regs + 2 xor hops,
// then O^T = V^T.P^T. K and V^T fragments load straight from global (L2-resident).
__launch_bounds__(256, 3)
__global__ void attn_v2(const u16* __restrict__ Qh, const u16* __restrict__ Kh,
                        const u16* __restrict__ Vt, u16* __restrict__ Ab) {
  const int tid = threadIdx.x, wave = tid >> 6, lane = tid & 63;
  const int l15 = lane & 15, l4 = lane >> 4;
  const int task = blockIdx.x * 4 + wave;          // [0, 3024)
  const int h = task / 252;
  const int rt = 251 - (task % 252);               // heavy first
  const int q0 = rt * 16;
  const int nkv = (q0 / FRAME + 1) * (FRAME / 64); // 64-key tiles

  __shared__ u16 sP[4][2048];                      // per-wave B-frag-ordered P buffer
  u16* pw = sP[wave];

  bf16x8 qf[4];
  {
    const u16* qb = Qh + ((size_t)h * S_LEN + q0 + l15) * HD + l4 * 8;
    #pragma unroll
    for (int ks = 0; ks < 4; ks++) qf[ks] = *(const bf16x8*)(qb + ks * 32);
  }
  f32x4 o[8];
  #pragma unroll
  for (int i = 0; i < 8; i++) o[i] = (f32x4){0.f, 0.f, 0.f, 0.f};
  float m_i = -1e30f, l_i = 0.f;

  const u16* kb0 = Kh + (size_t)h * S_LEN * HD;
  const u16* vb0 = Vt + (size_t)h * HD * S_PAD;

  for (int t = 0; t < nkv; ++t) {
    f32x4 sT[4];
    #pragma unroll
    for (int nt = 0; nt < 4; nt++) sT[nt] = (f32x4){0.f, 0.f, 0.f, 0.f};
    const u16* kb = kb0 + (size_t)t * 64 * HD;
    // QK in two K-halves to bound register pressure
    #pragma unroll
    for (int kh2 = 0; kh2 < 2; kh2++) {
      bf16x8 kf[4][2];
      #pragma unroll
      for (int nt = 0; nt < 4; nt++)
        #pragma unroll
        for (int ks = 0; ks < 2; ks++)
          kf[nt][ks] = *(const bf16x8*)(kb + (nt * 16 + l15) * HD + (kh2 * 2 + ks) * 32 + l4 * 8);
      #pragma unroll
      for (int ks = 0; ks < 2; ks++)
        #pragma unroll
        for (int nt = 0; nt < 4; nt++)
          sT[nt] = mfma16(kf[nt][ks], qf[kh2 * 2 + ks], sT[nt]);
    }
    // V^T fragment loads issued before softmax VALU to overlap latency
    bf16x8 vf[8][2];
    const u16* vb = vb0 + t * 64;
    #pragma unroll
    for (int vt = 0; vt < 8; vt++)
      #pragma unroll
      for (int ks2 = 0; ks2 < 2; ks2++)
        vf[vt][ks2] = *(const bf16x8*)(vb + (size_t)(vt * 16 + l15) * S_PAD + ks2 * 32 + l4 * 8);

    // online softmax over keys: reduce regs (16) then lane-groups (xor 16, 32)
    float mloc = -1e30f;
    #pragma unroll
    for (int nt = 0; nt < 4; nt++)
      #pragma unroll
      for (int r = 0; r < 4; r++) mloc = fmaxf(mloc, sT[nt][r]);
    mloc = fmaxf(mloc, __shfl_xor(mloc, 16, 64));
    mloc = fmaxf(mloc, __shfl_xor(mloc, 32, 64));
    float mn = fmaxf(m_i, mloc);
    float alpha = __expf(m_i - mn);
    m_i = mn;
    float rs = 0.f;
    #pragma unroll
    for (int nt = 0; nt < 4; nt++)
      #pragma unroll
      for (int r = 0; r < 4; r++) {
        float p = __expf(sT[nt][r] - mn);
        sT[nt][r] = p; rs += p;
      }
    rs += __shfl_xor(rs, 16, 64);
    rs += __shfl_xor(rs, 32, 64);
    l_i = l_i * alpha + rs;
    #pragma unroll
    for (int i = 0; i < 8; i++)
      #pragma unroll
      for (int r = 0; r < 4; r++) o[i][r] *= alpha;

    // P (S^T C-layout) -> LDS in exact B-frag lane order; reads are contiguous b128
    #pragma unroll
    for (int nt = 0; nt < 4; nt++) {
      u32 lo = (u32)f2bf(sT[nt][0]) | ((u32)f2bf(sT[nt][1]) << 16);
      u32 hi = (u32)f2bf(sT[nt][2]) | ((u32)f2bf(sT[nt][3]) << 16);
      u32 off = (u32)((nt >> 1) * 1024 + ((nt & 1) * 2 + (l4 >> 1)) * 128 + l15 * 8 + (l4 & 1) * 4);
      uint2 pk; pk.x = lo; pk.y = hi;
      *(uint2*)(pw + off) = pk;
    }
    #pragma unroll
    for (int ks2 = 0; ks2 < 2; ks2++) {
      bf16x8 pb = *(const bf16x8*)(pw + ks2 * 1024 + lane * 8);
      #pragma unroll
      for (int vt = 0; vt < 8; vt++)
        o[vt] = mfma16(vf[vt][ks2], pb, o[vt]);
    }
  }

  // O^T C-layout: col=q=l15, row=d=vt*16+l4*4+r -> pack 4 dims per 8B store
  float inv = 1.f / l_i;
  const size_t orow = (size_t)(q0 + l15) * DIMC + (size_t)((task / 252) * HD);
  #pragma unroll
  for (int vt = 0; vt < 8; vt++) {
    u32 lo = (u32)f2bf(o[vt][0] * inv) | ((u32)f2bf(o[vt][1] * inv) << 16);
    u32 hi = (u32)f2bf(o[vt][2] * inv) | ((u32)f2bf(o[vt][3] * inv) << 16);
    uint2 pk; pk.x = lo; pk.y = hi;
    *(uint2*)(Ab + orow + vt * 16 + l4 * 4) = pk;
  }
}

extern "C" void kernel_launch(void* const* d_in, const int* in_sizes, int n_in,
                              void* d_out, int out_size, void* d_ws, size_t ws_size,
                              hipStream_t stream) {
  if (ws_size < WS_NEED) return;
  char* ws = (char*)d_ws;
  int*   flag  = (int*)(ws + OFF_FLAG);
  float* canon = (float*)(ws + OFF_CANON);
  u16* xb    = (u16*)(ws + OFF_XB);
  u16* wqkvt = (u16*)(ws + OFF_WT);
  u16* wot   = (u16*)(ws + OFF_WOT);
  u16* yq    = (u16*)(ws + OFF_YQ);
  u16* yk    = (u16*)(ws + OFF_YK);
  u16* vt    = (u16*)(ws + OFF_VT);
  u16* qh    = (u16*)(ws + OFF_QH);
  u16* kh    = (u16*)(ws + OFF_KH);
  u16* ab    = (u16*)(ws + OFF_AT);

  const void* x  = d_in[0];
  const void* fr = d_in[3];
  const void* Wq = d_in[4];  const void* bq = d_in[5];
  const void* Wk = d_in[6];  const void* bk = d_in[7];
  const void* Wv = d_in[8];  const void* bv = d_in[9];
  const void* Wo = d_in[10]; const void* bo = d_in[11];
  const void* gq = d_in[12]; const void* gk = d_in[13];

  detect_dtype<<<1, 256, 0, stream>>>((const u16*)x, flag);
  prep_small<<<292, 256, 0, stream>>>(bq, bk, bv, bo, gq, gk, fr, canon, flag);
  convert_x<<<3072, 256, 0, stream>>>(x, xb, flag);
  transpose_w<<<dim3(48, 48, 4), dim3(32, 8), 0, stream>>>(Wq, Wk, Wv, Wo, wqkvt, wot, flag);
  gemm_bt<0><<<dim3(36, 32), 256, 0, stream>>>(xb, wqkvt, canon, yq, yk, vt, nullptr, flag);
  norm_rope<<<dim3(4032, 2), 256, 0, stream>>>(yq, yk, canon, qh, kh);
  attn_v2<<<756, 256, 0, stream>>>(qh, kh, vt, ab);
  gemm_bt<1><<<dim3(12, 32), 256, 0, stream>>>(ab, wot, canon, nullptr, nullptr, nullptr, d_out, flag);
}

// Round 3
// 386.018 us; speedup vs baseline: 2.3736x; 2.3736x over previous
//
#include <hip/hip_runtime.h>
#include <stdint.h>

typedef unsigned short u16;
typedef unsigned int u32;
typedef __attribute__((ext_vector_type(8))) short bf16x8;
typedef __attribute__((ext_vector_type(4))) float f32x4;

#define S_LEN 4032
#define S_PAD 4096
#define DIMC  1536
#define HD    128
#define FRAME 448

static const size_t OFF_FLAG  = 0;
static const size_t OFF_CANON = 256;
static const size_t OFF_XB    = 524288;
static const size_t OFF_WT    = OFF_XB  + 12582912;
static const size_t OFF_WOT   = OFF_WT  + 14155776;
static const size_t OFF_YQ    = OFF_WOT + 4718592;
static const size_t OFF_YK    = OFF_YQ  + 12582912;
static const size_t OFF_VT    = OFF_YK  + 12582912;
static const size_t OFF_QH    = OFF_VT  + 12582912;
static const size_t OFF_KH    = OFF_QH  + 12386304;
static const size_t OFF_AT    = OFF_KH  + 12386304;
static const size_t WS_NEED   = OFF_AT  + 12582912;

#define C_BQ 0
#define C_BO 4608
#define C_GQ 6144
#define C_GK 7680
#define C_FR 9216
#define C_TOT 74752

__device__ __forceinline__ u16 f2bf(float f) {
  union { float f; u32 u; } v; v.f = f;
  u32 u = v.u;
  u32 r = (u + 0x7fffu + ((u >> 16) & 1u)) >> 16;
  return (u16)r;
}
__device__ __forceinline__ float bf2f(u16 h) {
  union { float f; u32 u; } v; v.u = ((u32)h) << 16;
  return v.f;
}

__device__ __forceinline__ void gld_lds16(const void* g, void* l) {
  __builtin_amdgcn_global_load_lds(
      (const __attribute__((address_space(1))) void*)(uintptr_t)g,
      (__attribute__((address_space(3))) void*)(u32)(uintptr_t)l,
      16, 0, 0);
}

__device__ __forceinline__ f32x4 mfma16(bf16x8 a, bf16x8 b, f32x4 c) {
  return __builtin_amdgcn_mfma_f32_16x16x32_bf16(a, b, c, 0, 0, 0);
}

// ---------------- dtype detection ----------------
__global__ void detect_dtype(const u16* __restrict__ x, int* __restrict__ flag) {
  __shared__ int cnt;
  if (threadIdx.x == 0) cnt = 0;
  __syncthreads();
  int e = (x[2 * threadIdx.x] >> 7) & 0xff;
  if (e > 150) atomicAdd(&cnt, 1);
  __syncthreads();
  if (threadIdx.x == 0) *flag = (cnt >= 8) ? 1 : 0;
}

// ---------------- small tensors -> canonical fp32 ----------------
__global__ void prep_small(const void* bq, const void* bk, const void* bv, const void* bo,
                           const void* gq, const void* gk, const void* fr,
                           float* __restrict__ canon, const int* __restrict__ flagp) {
  int fl = *flagp;
  for (int i = blockIdx.x * 256 + threadIdx.x; i < C_TOT; i += gridDim.x * 256) {
    const void* src; int j;
    if      (i < 1536) { src = bq; j = i; }
    else if (i < 3072) { src = bk; j = i - 1536; }
    else if (i < 4608) { src = bv; j = i - 3072; }
    else if (i < 6144) { src = bo; j = i - 4608; }
    else if (i < 7680) { src = gq; j = i - 6144; }
    else if (i < 9216) { src = gk; j = i - 7680; }
    else               { src = fr; j = i - 9216; }
    canon[i] = fl ? ((const float*)src)[j] : bf2f(((const u16*)src)[j]);
  }
}

// ---------------- x -> bf16, pad rows to 4096 ----------------
__global__ void convert_x(const void* __restrict__ xin, u16* __restrict__ xb,
                          const int* __restrict__ flagp) {
  int fl = *flagp;
  int i = blockIdx.x * 256 + threadIdx.x;
  if (i >= (S_PAD * DIMC) / 8) return;
  size_t base = (size_t)i * 8;
  int row = (int)(base / DIMC);
  union { u16 h[8]; uint4 v; } u;
  if (row < S_LEN) {
    if (fl) {
      const float* xf = (const float*)xin + base;
      #pragma unroll
      for (int j = 0; j < 8; j++) u.h[j] = f2bf(xf[j]);
    } else {
      const u16* xh = (const u16*)xin + base;
      #pragma unroll
      for (int j = 0; j < 8; j++) u.h[j] = xh[j];
    }
  } else {
    #pragma unroll
    for (int j = 0; j < 8; j++) u.h[j] = 0;
  }
  ((uint4*)xb)[i] = u.v;
}

// ---------------- W (K x N) -> Wt (N x K) bf16 ----------------
__global__ void transpose_w(const void* Wq, const void* Wk, const void* Wv, const void* Wo,
                            u16* __restrict__ wqkvt, u16* __restrict__ wot,
                            const int* __restrict__ flagp) {
  int fl = *flagp;
  int z = blockIdx.z;
  const void* W = (z == 0) ? Wq : (z == 1) ? Wk : (z == 2) ? Wv : Wo;
  u16* dst = (z < 3) ? (wqkvt + (size_t)z * DIMC * DIMC) : wot;
  __shared__ float tile[32][33];
  int tx = threadIdx.x, ty = threadIdx.y;
  int c = blockIdx.x * 32 + tx;
  #pragma unroll
  for (int i = 0; i < 4; i++) {
    int r = blockIdx.y * 32 + ty + i * 8;
    float v = fl ? ((const float*)W)[(size_t)r * DIMC + c]
                 : bf2f(((const u16*)W)[(size_t)r * DIMC + c]);
    tile[ty + i * 8][tx] = v;
  }
  __syncthreads();
  int k = blockIdx.y * 32 + tx;
  #pragma unroll
  for (int i = 0; i < 4; i++) {
    int n = blockIdx.x * 32 + ty + i * 8;
    dst[(size_t)n * DIMC + k] = f2bf(tile[tx][ty + i * 8]);
  }
}

// ---------------- GEMM: C(MxN) = A(MxK) @ Bt(NxK)^T + bias ----------------
template <int MODE>
__launch_bounds__(256, 2)
__global__ void gemm_bt(const u16* __restrict__ A, const u16* __restrict__ Bt,
                        const float* __restrict__ canon,
                        u16* __restrict__ Yq, u16* __restrict__ Yk, u16* __restrict__ Vt,
                        void* __restrict__ Out, const int* __restrict__ flagp) {
  const int bm0 = blockIdx.y * 128, bn0 = blockIdx.x * 128;
  const int tid = threadIdx.x, wave = tid >> 6, lane = tid & 63;
  const int wm = wave >> 1, wn = wave & 1;
  const int l15 = lane & 15, l4 = lane >> 4;
  __shared__ u16 sA[128 * 64];
  __shared__ u16 sB[128 * 64];
  f32x4 acc[4][4];
  #pragma unroll
  for (int i = 0; i < 4; i++)
    #pragma unroll
    for (int j = 0; j < 4; j++) acc[i][j] = (f32x4){0.f, 0.f, 0.f, 0.f};

  const u16* Ab = A  + (size_t)(bm0 + (lane >> 3)) * DIMC + (lane & 7) * 8;
  const u16* Bb = Bt + (size_t)(bn0 + (lane >> 3)) * DIMC + (lane & 7) * 8;

  for (int kt = 0; kt < DIMC; kt += 64) {
    __syncthreads();
    #pragma unroll
    for (int c = 0; c < 4; c++) {
      int g = wave * 4 + c;
      gld_lds16(Ab + (size_t)g * 8 * DIMC + kt, (char*)sA + g * 1024);
      gld_lds16(Bb + (size_t)g * 8 * DIMC + kt, (char*)sB + g * 1024);
    }
    __syncthreads();
    #pragma unroll
    for (int ks = 0; ks < 2; ks++) {
      const int ko = ks * 32 + l4 * 8;
      bf16x8 av[4], bvv[4];
      #pragma unroll
      for (int mt = 0; mt < 4; mt++) av[mt]  = *(const bf16x8*)(sA + (wm * 64 + mt * 16 + l15) * 64 + ko);
      #pragma unroll
      for (int nt = 0; nt < 4; nt++) bvv[nt] = *(const bf16x8*)(sB + (wn * 64 + nt * 16 + l15) * 64 + ko);
      #pragma unroll
      for (int mt = 0; mt < 4; mt++)
        #pragma unroll
        for (int nt = 0; nt < 4; nt++)
          acc[mt][nt] = mfma16(av[mt], bvv[nt], acc[mt][nt]);
    }
  }

  const int gm0 = bm0 + wm * 64;
  const int gn0 = bn0 + wn * 64;
  if (MODE == 0) {
    #pragma unroll
    for (int nt = 0; nt < 4; nt++) {
      int gn = gn0 + nt * 16 + l15;
      float b = canon[C_BQ + gn];
      #pragma unroll
      for (int mt = 0; mt < 4; mt++) {
        int gm = gm0 + mt * 16 + l4 * 4;
        if (gn < 1536) {
          #pragma unroll
          for (int r = 0; r < 4; r++)
            Yq[(size_t)(gm + r) * DIMC + gn] = f2bf(acc[mt][nt][r] + b);
        } else if (gn < 3072) {
          int g2 = gn - 1536;
          #pragma unroll
          for (int r = 0; r < 4; r++)
            Yk[(size_t)(gm + r) * DIMC + g2] = f2bf(acc[mt][nt][r] + b);
        } else {
          int g2 = gn - 3072;
          u32 lo = (u32)f2bf(acc[mt][nt][0] + b) | ((u32)f2bf(acc[mt][nt][1] + b) << 16);
          u32 hi = (u32)f2bf(acc[mt][nt][2] + b) | ((u32)f2bf(acc[mt][nt][3] + b) << 16);
          uint2 pk; pk.x = lo; pk.y = hi;
          *(uint2*)(Vt + (size_t)g2 * S_PAD + gm) = pk;
        }
      }
    }
  } else {
    const int fl = *flagp;
    #pragma unroll
    for (int nt = 0; nt < 4; nt++) {
      int gn = gn0 + nt * 16 + l15;
      float b = canon[C_BO + gn];
      #pragma unroll
      for (int mt = 0; mt < 4; mt++) {
        int gm = gm0 + mt * 16 + l4 * 4;
        #pragma unroll
        for (int r = 0; r < 4; r++) {
          int gr = gm + r;
          if (gr < S_LEN) {
            float v = acc[mt][nt][r] + b;
            if (fl) ((float*)Out)[(size_t)gr * DIMC + gn] = v;
            else    ((u16*)Out)[(size_t)gr * DIMC + gn] = f2bf(v);
          }
        }
      }
    }
  }
}

// ---------------- fused RMSNorm + RoPE (q scaled by 1/sqrt(HD)) ----------------
__global__ void norm_rope(const u16* __restrict__ Yq, const u16* __restrict__ Yk,
                          const float* __restrict__ canon, u16* __restrict__ Qh,
                          u16* __restrict__ Kh) {
  const int s = blockIdx.x;
  const int isq = (blockIdx.y == 0);
  const u16* Y = isq ? Yq : Yk;
  const float* g = canon + (isq ? C_GQ : C_GK);
  u16* Oh = isq ? Qh : Kh;
  const float sc = isq ? 0.08838834764831845f : 1.0f;
  const int tid = threadIdx.x, wave = tid >> 6, lane = tid & 63;
  __shared__ float row[DIMC];
  __shared__ float cs[64], sn[64];
  __shared__ float red[4];
  float ss = 0.f;
  for (int i = tid; i < DIMC; i += 256) {
    float v = bf2f(Y[(size_t)s * DIMC + i]);
    row[i] = v; ss += v * v;
  }
  #pragma unroll
  for (int d = 32; d; d >>= 1) ss += __shfl_down(ss, d, 64);
  if (lane == 0) red[wave] = ss;
  if (tid < 64) {
    int f_ = s / FRAME, hh = (s % FRAME) / 28, ww = s % 28;
    const float* fr = canon + C_FR;
    float a;
    if (tid < 22)      a = fr[f_ * 64 + tid];
    else if (tid < 43) a = fr[hh * 64 + tid];
    else               a = fr[ww * 64 + tid];
    float si, co;
    __sincosf(a, &si, &co);
    cs[tid] = co; sn[tid] = si;
  }
  __syncthreads();
  float rms = rsqrtf((red[0] + red[1] + red[2] + red[3]) * (1.f / 1536.f) + 1e-6f);
  for (int p = tid; p < 768; p += 256) {
    int head = p >> 6, jj = p & 63;
    float xr = row[2 * p]     * rms * g[2 * p];
    float xi = row[2 * p + 1] * rms * g[2 * p + 1];
    float c = cs[jj], s_ = sn[jj];
    u32 pk = (u32)f2bf((xr * c - xi * s_) * sc) | ((u32)f2bf((xr * s_ + xi * c) * sc) << 16);
    *(u32*)(Oh + ((size_t)head * S_LEN + s) * HD + 2 * jj) = pk;
  }
}

// ---------------- flash attention v3: LDS-staged KV (XOR-swizzled) + S^T softmax ----------------
// Block = 64 q rows x 1 head; wave w owns 16 q rows. K/V tiles shared via LDS.
// Swizzle: K chunk c at (row, c^(row&15)); V^T chunk c at (row, c^(row&7)) ->
// every quarter-wave ds_read_b128 lands 2 accesses/bank (free, m136).
__launch_bounds__(256, 3)
__global__ void attn_v3(const u16* __restrict__ Qh, const u16* __restrict__ Kh,
                        const u16* __restrict__ Vt, u16* __restrict__ Ab) {
  const int tid = threadIdx.x, wave = tid >> 6, lane = tid & 63;
  const int l15 = lane & 15, l4 = lane >> 4;
  const int h = blockIdx.x % 12;
  const int qb = 62 - (blockIdx.x / 12);     // heavy (long-kv) blocks first
  const int q0 = qb * 64;
  const int nkv = (q0 / FRAME + 1) * 7;      // 64-key tiles
  __shared__ u16 sK[8192];                   // 64 x 128, swizzled
  __shared__ u16 sV[8192];                   // 128 x 64, swizzled
  __shared__ u16 sP[4][1024];                // per-wave P^T in B-frag order
  u16* pw = sP[wave];

  // per-lane swizzled source offsets for global_load_lds (constant over tiles)
  int koff[4], voff[4];
  #pragma unroll
  for (int i = 0; i < 4; i++) {
    int s = (wave * 4 + i) * 64 + lane;
    int r = s >> 4, c = (s & 15) ^ (r & 15);
    koff[i] = r * HD + c * 8;
    int rv = s >> 3, cv = (s & 7) ^ (rv & 7);
    voff[i] = rv * S_PAD + cv * 8;
  }

  bf16x8 qf[4];
  {
    const u16* qp = Qh + ((size_t)h * S_LEN + q0 + wave * 16 + l15) * HD + l4 * 8;
    #pragma unroll
    for (int ks = 0; ks < 4; ks++) qf[ks] = *(const bf16x8*)(qp + ks * 32);
  }
  f32x4 o[8];
  #pragma unroll
  for (int i = 0; i < 8; i++) o[i] = (f32x4){0.f, 0.f, 0.f, 0.f};
  float m_i = -1e30f, l_i = 0.f;

  const u16* kb0 = Kh + (size_t)h * S_LEN * HD;
  const u16* vb0 = Vt + (size_t)h * HD * S_PAD;

  for (int t = 0; t < nkv; ++t) {
    __syncthreads();   // prior-tile readers done
    {
      const u16* kb = kb0 + (size_t)t * 64 * HD;
      const u16* vb = vb0 + t * 64;
      #pragma unroll
      for (int i = 0; i < 4; i++) {
        gld_lds16(kb + koff[i], (char*)sK + (wave * 4 + i) * 1024);
        gld_lds16(vb + voff[i], (char*)sV + (wave * 4 + i) * 1024);
      }
    }
    __syncthreads();   // staging visible (compiler drains vmcnt)

    // S^T = K . Q^T : A = K-frag (rows = keys), B = Q-frag (cols = q)
    f32x4 sT[4];
    #pragma unroll
    for (int nt = 0; nt < 4; nt++) sT[nt] = (f32x4){0.f, 0.f, 0.f, 0.f};
    #pragma unroll
    for (int ks = 0; ks < 4; ks++) {
      bf16x8 kf[4];
      #pragma unroll
      for (int nt = 0; nt < 4; nt++)
        kf[nt] = *(const bf16x8*)(sK + (nt * 16 + l15) * HD + (((ks * 4 + l4) ^ l15) * 8));
      #pragma unroll
      for (int nt = 0; nt < 4; nt++)
        sT[nt] = mfma16(kf[nt], qf[ks], sT[nt]);
    }

    // online softmax over keys (regs + 2 xor hops over l4 groups)
    float mloc = -1e30f;
    #pragma unroll
    for (int nt = 0; nt < 4; nt++)
      #pragma unroll
      for (int r = 0; r < 4; r++) mloc = fmaxf(mloc, sT[nt][r]);
    mloc = fmaxf(mloc, __shfl_xor(mloc, 16, 64));
    mloc = fmaxf(mloc, __shfl_xor(mloc, 32, 64));
    float mn = fmaxf(m_i, mloc);
    float alpha = __expf(m_i - mn);
    m_i = mn;
    float rs = 0.f;
    #pragma unroll
    for (int nt = 0; nt < 4; nt++)
      #pragma unroll
      for (int r = 0; r < 4; r++) {
        float p = __expf(sT[nt][r] - mn);
        sT[nt][r] = p; rs += p;
      }
    rs += __shfl_xor(rs, 16, 64);
    rs += __shfl_xor(rs, 32, 64);
    l_i = l_i * alpha + rs;
    #pragma unroll
    for (int i = 0; i < 8; i++)
      #pragma unroll
      for (int r = 0; r < 4; r++) o[i][r] *= alpha;

    // P^T (C-layout) -> per-wave LDS in exact B-frag order (verified mapping, R2)
    #pragma unroll
    for (int nt = 0; nt < 4; nt++) {
      u32 lo = (u32)f2bf(sT[nt][0]) | ((u32)f2bf(sT[nt][1]) << 16);
      u32 hi = (u32)f2bf(sT[nt][2]) | ((u32)f2bf(sT[nt][3]) << 16);
      u32 off = (u32)((nt >> 1) * 512 + ((nt & 1) * 2 + (l4 >> 1)) * 128 + l15 * 8 + (l4 & 1) * 4);
      uint2 pk; pk.x = lo; pk.y = hi;
      *(uint2*)(pw + off) = pk;
    }
    // O^T += V^T . P^T : A = V^T-frag (rows = dims), B = P^T-frag
    #pragma unroll
    for (int ks2 = 0; ks2 < 2; ks2++) {
      bf16x8 pb = *(const bf16x8*)(pw + ks2 * 512 + lane * 8);
      #pragma unroll
      for (int vt = 0; vt < 8; vt++) {
        bf16x8 vf = *(const bf16x8*)(sV + (vt * 16 + l15) * 64 + (((ks2 * 4 + l4) ^ (l15 & 7)) * 8));
        o[vt] = mfma16(vf, pb, o[vt]);
      }
    }
  }

  // O^T C-layout: col = q = l15, row = dim = vt*16 + l4*4 + r
  float inv = 1.f / l_i;
  const size_t orow = (size_t)(q0 + wave * 16 + l15) * DIMC + (size_t)h * HD;
  #pragma unroll
  for (int vt = 0; vt < 8; vt++) {
    u32 lo = (u32)f2bf(o[vt][0] * inv) | ((u32)f2bf(o[vt][1] * inv) << 16);
    u32 hi = (u32)f2bf(o[vt][2] * inv) | ((u32)f2bf(o[vt][3] * inv) << 16);
    uint2 pk; pk.x = lo; pk.y = hi;
    *(uint2*)(Ab + orow + vt * 16 + l4 * 4) = pk;
  }
}

extern "C" void kernel_launch(void* const* d_in, const int* in_sizes, int n_in,
                              void* d_out, int out_size, void* d_ws, size_t ws_size,
                              hipStream_t stream) {
  if (ws_size < WS_NEED) return;
  char* ws = (char*)d_ws;
  int*   flag  = (int*)(ws + OFF_FLAG);
  float* canon = (float*)(ws + OFF_CANON);
  u16* xb    = (u16*)(ws + OFF_XB);
  u16* wqkvt = (u16*)(ws + OFF_WT);
  u16* wot   = (u16*)(ws + OFF_WOT);
  u16* yq    = (u16*)(ws + OFF_YQ);
  u16* yk    = (u16*)(ws + OFF_YK);
  u16* vt    = (u16*)(ws + OFF_VT);
  u16* qh    = (u16*)(ws + OFF_QH);
  u16* kh    = (u16*)(ws + OFF_KH);
  u16* ab    = (u16*)(ws + OFF_AT);

  const void* x  = d_in[0];
  const void* fr = d_in[3];
  const void* Wq = d_in[4];  const void* bq = d_in[5];
  const void* Wk = d_in[6];  const void* bk = d_in[7];
  const void* Wv = d_in[8];  const void* bv = d_in[9];
  const void* Wo = d_in[10]; const void* bo = d_in[11];
  const void* gq = d_in[12]; const void* gk = d_in[13];

  detect_dtype<<<1, 256, 0, stream>>>((const u16*)x, flag);
  prep_small<<<292, 256, 0, stream>>>(bq, bk, bv, bo, gq, gk, fr, canon, flag);
  convert_x<<<3072, 256, 0, stream>>>(x, xb, flag);
  transpose_w<<<dim3(48, 48, 4), dim3(32, 8), 0, stream>>>(Wq, Wk, Wv, Wo, wqkvt, wot, flag);
  gemm_bt<0><<<dim3(36, 32), 256, 0, stream>>>(xb, wqkvt, canon, yq, yk, vt, nullptr, flag);
  norm_rope<<<dim3(4032, 2), 256, 0, stream>>>(yq, yk, canon, qh, kh);
  attn_v3<<<756, 256, 0, stream>>>(qh, kh, vt, ab);
  gemm_bt<1><<<dim3(12, 32), 256, 0, stream>>>(ab, wot, canon, nullptr, nullptr, nullptr, d_out, flag);
}